// Round 1
// baseline (423.279 us; speedup 1.0000x reference)
//
#include <hip/hip_runtime.h>
#include <math.h>

#define B 4
#define C 64
#define H 256
#define W 256
#define CMID 16
#define CIN 73        // 64 + 9
#define HW (H*W)

// ---------------------------------------------------------------------------
// Tiny weight transpose: w1 (CMID, CIN, 3, 3) -> wt[(ci*9+k)*CMID + co]
// so conv1's inner loop reads 16 consecutive floats at a wave-uniform address.
// ---------------------------------------------------------------------------
__global__ void transpose_w1_kernel(const float* __restrict__ w1, float* __restrict__ wt) {
    int tid = blockIdx.x * blockDim.x + threadIdx.x;
    if (tid >= CMID * CIN * 9) return;
    int co = tid & (CMID - 1);
    int rest = tid >> 4;          // ci*9 + k
    int ci = rest / 9;
    int k = rest - ci * 9;
    wt[tid] = w1[(co * CIN + ci) * 9 + k];
}

// ---------------------------------------------------------------------------
// Local cosine similarity: one thread per (b,y,x). One pass over 64 channels
// accumulating center sqnorm, 8 neighbor sqnorms, 9 dots.
// sim layout: (B, 9, H, W)
// ---------------------------------------------------------------------------
__global__ void sim_kernel(const float* __restrict__ x, float* __restrict__ sim) {
    int idx = blockIdx.x * blockDim.x + threadIdx.x;
    int px = idx & (W - 1);
    int py = (idx >> 8) & (H - 1);
    int b  = idx >> 16;

    const float* base = x + (size_t)b * C * HW + py * W + px;

    float dot[9], nsq[9], csq = 0.f;
#pragma unroll
    for (int k = 0; k < 9; ++k) { dot[k] = 0.f; nsq[k] = 0.f; }

    const bool vy0 = py > 0, vy2 = py < H - 1;
    const bool vx0 = px > 0, vx2 = px < W - 1;
    const bool valid[9] = { vy0 && vx0, vy0, vy0 && vx2,
                            vx0,        true, vx2,
                            vy2 && vx0, vy2, vy2 && vx2 };
    const int off[9] = { -W - 1, -W, -W + 1, -1, 0, 1, W - 1, W, W + 1 };

    for (int c = 0; c < C; ++c) {
        const float* p = base + (size_t)c * HW;
        float cv = p[0];
        csq = fmaf(cv, cv, csq);
#pragma unroll
        for (int k = 0; k < 9; ++k) {
            if (k == 4) continue;
            float nv = valid[k] ? p[off[k]] : 0.f;
            dot[k] = fmaf(cv, nv, dot[k]);
            nsq[k] = fmaf(nv, nv, nsq[k]);
        }
    }
    dot[4] = csq;
    nsq[4] = csq;

    float cn = sqrtf(csq) + 1e-8f;
    float* so = sim + (size_t)b * 9 * HW + py * W + px;
#pragma unroll
    for (int k = 0; k < 9; ++k) {
        float nn = sqrtf(nsq[k]) + 1e-8f;
        so[(size_t)k * HW] = dot[k] / (cn * nn);
    }
}

// ---------------------------------------------------------------------------
// Conv1 (73 -> 16, 3x3, pad 1) + leaky relu(0.2). Thread per pixel,
// 16 fp32 accumulators, weights read at wave-uniform addresses (scalar path).
// h layout: (B, 16, H, W)
// ---------------------------------------------------------------------------
__global__ void conv1_kernel(const float* __restrict__ x, const float* __restrict__ sim,
                             const float* __restrict__ wt, const float* __restrict__ b1,
                             float* __restrict__ h) {
    int idx = blockIdx.x * blockDim.x + threadIdx.x;
    int px = idx & (W - 1);
    int py = (idx >> 8) & (H - 1);
    int b  = idx >> 16;

    float acc[CMID];
#pragma unroll
    for (int co = 0; co < CMID; ++co) acc[co] = b1[co];

    const bool vy0 = py > 0, vy2 = py < H - 1;
    const bool vx0 = px > 0, vx2 = px < W - 1;
    const bool valid[9] = { vy0 && vx0, vy0, vy0 && vx2,
                            vx0,        true, vx2,
                            vy2 && vx0, vy2, vy2 && vx2 };
    const int off[9] = { -W - 1, -W, -W + 1, -1, 0, 1, W - 1, W, W + 1 };

    int pix = py * W + px;
    const float* xb = x   + (size_t)b * C * HW + pix;
    const float* sb = sim + (size_t)b * 9 * HW + pix;

    // x channels
    for (int ci = 0; ci < C; ++ci) {
        const float* p  = xb + (size_t)ci * HW;
        const float* wp = wt + ci * 9 * CMID;
#pragma unroll
        for (int k = 0; k < 9; ++k) {
            float v = valid[k] ? p[off[k]] : 0.f;
#pragma unroll
            for (int co = 0; co < CMID; ++co)
                acc[co] = fmaf(v, wp[k * CMID + co], acc[co]);
        }
    }
    // sim channels
    for (int ci = 0; ci < 9; ++ci) {
        const float* p  = sb + (size_t)ci * HW;
        const float* wp = wt + (C + ci) * 9 * CMID;
#pragma unroll
        for (int k = 0; k < 9; ++k) {
            float v = valid[k] ? p[off[k]] : 0.f;
#pragma unroll
            for (int co = 0; co < CMID; ++co)
                acc[co] = fmaf(v, wp[k * CMID + co], acc[co]);
        }
    }

    float* ho = h + (size_t)b * CMID * HW + pix;
#pragma unroll
    for (int co = 0; co < CMID; ++co) {
        float v = acc[co];
        ho[(size_t)co * HW] = v >= 0.f ? v : 0.2f * v;
    }
}

// ---------------------------------------------------------------------------
// Conv2 (16 -> 2, 3x3, pad 1) + tanh*0.1 + bilinear grid sample (border clamp).
// Thread per pixel; loops 64 channels for the gather.
// ---------------------------------------------------------------------------
__global__ void conv2_sample_kernel(const float* __restrict__ x, const float* __restrict__ h,
                                    const float* __restrict__ w2, const float* __restrict__ b2,
                                    float* __restrict__ out) {
    int idx = blockIdx.x * blockDim.x + threadIdx.x;
    int px = idx & (W - 1);
    int py = (idx >> 8) & (H - 1);
    int b  = idx >> 16;

    const bool vy0 = py > 0, vy2 = py < H - 1;
    const bool vx0 = px > 0, vx2 = px < W - 1;
    const bool valid[9] = { vy0 && vx0, vy0, vy0 && vx2,
                            vx0,        true, vx2,
                            vy2 && vx0, vy2, vy2 && vx2 };
    const int off[9] = { -W - 1, -W, -W + 1, -1, 0, 1, W - 1, W, W + 1 };

    int pix = py * W + px;
    const float* hb = h + (size_t)b * CMID * HW + pix;

    float acc0 = b2[0], acc1 = b2[1];
    for (int ci = 0; ci < CMID; ++ci) {
        const float* p = hb + (size_t)ci * HW;
#pragma unroll
        for (int k = 0; k < 9; ++k) {
            float v = valid[k] ? p[off[k]] : 0.f;
            acc0 = fmaf(v, w2[ci * 9 + k], acc0);
            acc1 = fmaf(v, w2[(CMID + ci) * 9 + k], acc1);
        }
    }

    float ox = 0.1f * tanhf(acc0);
    float oy = 0.1f * tanhf(acc1);

    // ix = px + ox * (W-1)/2, iy = py + oy * (H-1)/2, clipped to borders
    float ix = (float)px + ox * (0.5f * (float)(W - 1));
    float iy = (float)py + oy * (0.5f * (float)(H - 1));
    ix = fminf(fmaxf(ix, 0.f), (float)(W - 1));
    iy = fminf(fmaxf(iy, 0.f), (float)(H - 1));

    float x0f = floorf(ix), y0f = floorf(iy);
    float wx = ix - x0f, wy = iy - y0f;
    int x0 = (int)x0f, y0 = (int)y0f;
    int x1 = min(x0 + 1, W - 1), y1 = min(y0 + 1, H - 1);

    int i00 = y0 * W + x0, i01 = y0 * W + x1;
    int i10 = y1 * W + x0, i11 = y1 * W + x1;

    const float* xb = x + (size_t)b * C * HW;
    float* ob = out + (size_t)b * C * HW + pix;

    for (int c = 0; c < C; ++c) {
        const float* img = xb + (size_t)c * HW;
        float v00 = img[i00], v01 = img[i01], v10 = img[i10], v11 = img[i11];
        float top = (1.f - wx) * v00 + wx * v01;
        float bot = (1.f - wx) * v10 + wx * v11;
        ob[(size_t)c * HW] = (1.f - wy) * top + wy * bot;
    }
}

// ---------------------------------------------------------------------------
extern "C" void kernel_launch(void* const* d_in, const int* in_sizes, int n_in,
                              void* d_out, int out_size, void* d_ws, size_t ws_size,
                              hipStream_t stream) {
    const float* x  = (const float*)d_in[0];
    const float* w1 = (const float*)d_in[1];
    const float* b1 = (const float*)d_in[2];
    const float* w2 = (const float*)d_in[3];
    const float* b2 = (const float*)d_in[4];
    float* out = (float*)d_out;

    float* ws  = (float*)d_ws;
    float* wt  = ws;                                   // 10512 floats (pad to 16384)
    float* sim = ws + 16384;                           // B*9*HW  = 2359296 floats
    float* h   = sim + (size_t)B * 9 * HW;             // B*16*HW = 4194304 floats

    int nw = CMID * CIN * 9;
    transpose_w1_kernel<<<(nw + 255) / 256, 256, 0, stream>>>(w1, wt);

    int npix = B * HW;   // 262144
    sim_kernel<<<npix / 256, 256, 0, stream>>>(x, sim);
    conv1_kernel<<<npix / 256, 256, 0, stream>>>(x, sim, wt, b1, h);
    conv2_sample_kernel<<<npix / 256, 256, 0, stream>>>(x, h, w2, b2, out);
}

// Round 2
// 407.186 us; speedup vs baseline: 1.0395x; 1.0395x over previous
//
#include <hip/hip_runtime.h>
#include <math.h>

#define B 4
#define C 64
#define H 256
#define W 256
#define CMID 16
#define CIN 73        // 64 + 9
#define HW (H*W)
#define NW (CIN*9*CMID)   // 10512 weights for conv1

// ---------------------------------------------------------------------------
// w1 (CMID, CIN, 3, 3) -> wt[(ci*9+k)*CMID + co]  (inner = 16 consecutive co)
// ---------------------------------------------------------------------------
__global__ void transpose_w1_kernel(const float* __restrict__ w1, float* __restrict__ wt) {
    int tid = blockIdx.x * blockDim.x + threadIdx.x;
    if (tid >= NW) return;
    int co = tid & (CMID - 1);
    int rest = tid >> 4;          // ci*9 + k
    int ci = rest / 9;
    int k = rest - ci * 9;
    wt[tid] = w1[(co * CIN + ci) * 9 + k];
}

// ---------------------------------------------------------------------------
// Helper: load a 3x4 stencil patch (rows y-1..y+1, cols x-1..x+2) with
// zero-padding masks. Serves two horizontally-adjacent pixels.
// ---------------------------------------------------------------------------
__device__ __forceinline__ void load_patch(const float* __restrict__ p,
                                           bool r0, bool r2, bool c0ok, bool c3ok,
                                           float v[3][4]) {
#pragma unroll
    for (int r = 0; r < 3; ++r) {
        bool rok = (r == 0) ? r0 : ((r == 2) ? r2 : true);
        const float* rp = p + (r - 1) * W;
        v[r][0] = (rok && c0ok) ? rp[-1] : 0.f;
        v[r][1] = rok ? rp[0] : 0.f;
        v[r][2] = rok ? rp[1] : 0.f;
        v[r][3] = (rok && c3ok) ? rp[2] : 0.f;
    }
}

// ---------------------------------------------------------------------------
// Local cosine similarity, 2 pixels/thread. sim layout (B, 9, H, W).
// ---------------------------------------------------------------------------
__global__ __launch_bounds__(256) void sim_kernel(const float* __restrict__ x,
                                                  float* __restrict__ sim) {
    int t = blockIdx.x * blockDim.x + threadIdx.x;
    int base = t * 2;
    int px = base & (W - 1);
    int py = (base >> 8) & (H - 1);
    int b  = base >> 16;
    int pix = py * W + px;

    const bool r0 = py > 0, r2 = py < H - 1;
    const bool c0ok = px > 0, c3ok = (px + 2) < W;

    const float* xb = x + (size_t)b * C * HW + pix;

    float csq0 = 0.f, csq1 = 0.f;
    float dot0[9], dot1[9], nsq0[9], nsq1[9];
#pragma unroll
    for (int k = 0; k < 9; ++k) { dot0[k] = dot1[k] = nsq0[k] = nsq1[k] = 0.f; }

    for (int ci = 0; ci < C; ++ci) {
        float v[3][4];
        load_patch(xb + (size_t)ci * HW, r0, r2, c0ok, c3ok, v);
        float cv0 = v[1][1], cv1 = v[1][2];
        csq0 = fmaf(cv0, cv0, csq0);
        csq1 = fmaf(cv1, cv1, csq1);
#pragma unroll
        for (int kr = 0; kr < 3; ++kr)
#pragma unroll
            for (int kc = 0; kc < 3; ++kc) {
                int k = kr * 3 + kc;
                if (k == 4) continue;
                float n0 = v[kr][kc], n1 = v[kr][kc + 1];
                dot0[k] = fmaf(cv0, n0, dot0[k]);
                nsq0[k] = fmaf(n0, n0, nsq0[k]);
                dot1[k] = fmaf(cv1, n1, dot1[k]);
                nsq1[k] = fmaf(n1, n1, nsq1[k]);
            }
    }
    dot0[4] = csq0; nsq0[4] = csq0;
    dot1[4] = csq1; nsq1[4] = csq1;

    float cn0 = sqrtf(csq0) + 1e-8f;
    float cn1 = sqrtf(csq1) + 1e-8f;
    float* so = sim + (size_t)b * 9 * HW + pix;
#pragma unroll
    for (int k = 0; k < 9; ++k) {
        float s0 = dot0[k] / (cn0 * (sqrtf(nsq0[k]) + 1e-8f));
        float s1 = dot1[k] / (cn1 * (sqrtf(nsq1[k]) + 1e-8f));
        *(float2*)(so + (size_t)k * HW) = make_float2(s0, s1);
    }
}

// ---------------------------------------------------------------------------
// Conv1 (73 -> 16, 3x3, pad 1) + leaky relu. 2 pixels/thread, weights in LDS.
// ---------------------------------------------------------------------------
__global__ __launch_bounds__(256) void conv1_kernel(const float* __restrict__ x,
                                                    const float* __restrict__ sim,
                                                    const float* __restrict__ wt,
                                                    const float* __restrict__ b1,
                                                    float* __restrict__ h) {
    __shared__ float4 lw4[NW / 4];
    {
        const float4* src = (const float4*)wt;
        for (int i = threadIdx.x; i < NW / 4; i += 256) lw4[i] = src[i];
    }
    __syncthreads();
    const float* lw = (const float*)lw4;

    int t = blockIdx.x * blockDim.x + threadIdx.x;
    int base = t * 2;
    int px = base & (W - 1);
    int py = (base >> 8) & (H - 1);
    int b  = base >> 16;
    int pix = py * W + px;

    const bool r0 = py > 0, r2 = py < H - 1;
    const bool c0ok = px > 0, c3ok = (px + 2) < W;

    const float* xb = x   + (size_t)b * C * HW + pix;
    const float* sb = sim + (size_t)b * 9 * HW + pix;

    float acc0[CMID], acc1[CMID];
#pragma unroll
    for (int co = 0; co < CMID; ++co) { acc0[co] = b1[co]; acc1[co] = b1[co]; }

#pragma unroll 1
    for (int ci = 0; ci < CIN; ++ci) {
        const float* p = (ci < C) ? (xb + (size_t)ci * HW)
                                  : (sb + (size_t)(ci - C) * HW);
        float v[3][4];
        load_patch(p, r0, r2, c0ok, c3ok, v);

        const float* wp = lw + ci * 9 * CMID;
#pragma unroll
        for (int kr = 0; kr < 3; ++kr)
#pragma unroll
            for (int kc = 0; kc < 3; ++kc) {
                float a0 = v[kr][kc], a1 = v[kr][kc + 1];
                const float4* w4 = (const float4*)(wp + (kr * 3 + kc) * CMID);
#pragma unroll
                for (int q = 0; q < 4; ++q) {
                    float4 wv = w4[q];
                    acc0[4 * q + 0] = fmaf(a0, wv.x, acc0[4 * q + 0]);
                    acc0[4 * q + 1] = fmaf(a0, wv.y, acc0[4 * q + 1]);
                    acc0[4 * q + 2] = fmaf(a0, wv.z, acc0[4 * q + 2]);
                    acc0[4 * q + 3] = fmaf(a0, wv.w, acc0[4 * q + 3]);
                    acc1[4 * q + 0] = fmaf(a1, wv.x, acc1[4 * q + 0]);
                    acc1[4 * q + 1] = fmaf(a1, wv.y, acc1[4 * q + 1]);
                    acc1[4 * q + 2] = fmaf(a1, wv.z, acc1[4 * q + 2]);
                    acc1[4 * q + 3] = fmaf(a1, wv.w, acc1[4 * q + 3]);
                }
            }
    }

    float* ho = h + (size_t)b * CMID * HW + pix;
#pragma unroll
    for (int co = 0; co < CMID; ++co) {
        float v0 = acc0[co], v1 = acc1[co];
        v0 = v0 >= 0.f ? v0 : 0.2f * v0;
        v1 = v1 >= 0.f ? v1 : 0.2f * v1;
        *(float2*)(ho + (size_t)co * HW) = make_float2(v0, v1);
    }
}

// ---------------------------------------------------------------------------
// Conv2 (16 -> 2) + tanh*0.1 + bilinear border grid-sample. 2 pixels/thread.
// ---------------------------------------------------------------------------
__global__ __launch_bounds__(256) void conv2_sample_kernel(const float* __restrict__ x,
                                                           const float* __restrict__ h,
                                                           const float* __restrict__ w2,
                                                           const float* __restrict__ b2,
                                                           float* __restrict__ out) {
    __shared__ float lw2[CMID * 9 * 2];
    for (int i = threadIdx.x; i < CMID * 9 * 2; i += 256) {
        int co = i & 1;
        int rest = i >> 1;      // ci*9 + k
        int ci = rest / 9;
        int k = rest - ci * 9;
        lw2[i] = w2[(co * CMID + ci) * 9 + k];
    }
    __syncthreads();

    int t = blockIdx.x * blockDim.x + threadIdx.x;
    int base = t * 2;
    int px = base & (W - 1);
    int py = (base >> 8) & (H - 1);
    int b  = base >> 16;
    int pix = py * W + px;

    const bool r0 = py > 0, r2 = py < H - 1;
    const bool c0ok = px > 0, c3ok = (px + 2) < W;

    const float* hb = h + (size_t)b * CMID * HW + pix;

    float a00 = b2[0], a01 = b2[1];   // px0: (offx, offy)
    float a10 = b2[0], a11 = b2[1];   // px1

#pragma unroll 1
    for (int ci = 0; ci < CMID; ++ci) {
        float v[3][4];
        load_patch(hb + (size_t)ci * HW, r0, r2, c0ok, c3ok, v);
#pragma unroll
        for (int kr = 0; kr < 3; ++kr)
#pragma unroll
            for (int kc = 0; kc < 3; ++kc) {
                int k = kr * 3 + kc;
                float2 wv = *(const float2*)(lw2 + (ci * 9 + k) * 2);
                a00 = fmaf(v[kr][kc],     wv.x, a00);
                a01 = fmaf(v[kr][kc],     wv.y, a01);
                a10 = fmaf(v[kr][kc + 1], wv.x, a10);
                a11 = fmaf(v[kr][kc + 1], wv.y, a11);
            }
    }

    // offsets -> sample coords (border-clamped)
    float ix0 = (float)px       + 0.1f * tanhf(a00) * (0.5f * (float)(W - 1));
    float iy0 = (float)py       + 0.1f * tanhf(a01) * (0.5f * (float)(H - 1));
    float ix1 = (float)(px + 1) + 0.1f * tanhf(a10) * (0.5f * (float)(W - 1));
    float iy1 = (float)py       + 0.1f * tanhf(a11) * (0.5f * (float)(H - 1));

    ix0 = fminf(fmaxf(ix0, 0.f), (float)(W - 1));
    iy0 = fminf(fmaxf(iy0, 0.f), (float)(H - 1));
    ix1 = fminf(fmaxf(ix1, 0.f), (float)(W - 1));
    iy1 = fminf(fmaxf(iy1, 0.f), (float)(H - 1));

    float x0f0 = floorf(ix0), y0f0 = floorf(iy0);
    float x0f1 = floorf(ix1), y0f1 = floorf(iy1);
    float wx0 = ix0 - x0f0, wy0 = iy0 - y0f0;
    float wx1 = ix1 - x0f1, wy1 = iy1 - y0f1;
    int x00 = (int)x0f0, y00 = (int)y0f0;
    int x01 = (int)x0f1, y01 = (int)y0f1;
    int x10 = min(x00 + 1, W - 1), y10 = min(y00 + 1, H - 1);
    int x11 = min(x01 + 1, W - 1), y11 = min(y01 + 1, H - 1);

    int i00_0 = y00 * W + x00, i01_0 = y00 * W + x10;
    int i10_0 = y10 * W + x00, i11_0 = y10 * W + x10;
    int i00_1 = y01 * W + x01, i01_1 = y01 * W + x11;
    int i10_1 = y11 * W + x01, i11_1 = y11 * W + x11;

    const float* xb = x + (size_t)b * C * HW;
    float* ob = out + (size_t)b * C * HW + pix;

    for (int c = 0; c < C; ++c) {
        const float* img = xb + (size_t)c * HW;
        float v00 = img[i00_0], v01 = img[i01_0], v10 = img[i10_0], v11 = img[i11_0];
        float top0 = fmaf(wx0, v01 - v00, v00);
        float bot0 = fmaf(wx0, v11 - v10, v10);
        float o0 = fmaf(wy0, bot0 - top0, top0);
        float u00 = img[i00_1], u01 = img[i01_1], u10 = img[i10_1], u11 = img[i11_1];
        float top1 = fmaf(wx1, u01 - u00, u00);
        float bot1 = fmaf(wx1, u11 - u10, u10);
        float o1 = fmaf(wy1, bot1 - top1, top1);
        *(float2*)(ob + (size_t)c * HW) = make_float2(o0, o1);
    }
}

// ---------------------------------------------------------------------------
extern "C" void kernel_launch(void* const* d_in, const int* in_sizes, int n_in,
                              void* d_out, int out_size, void* d_ws, size_t ws_size,
                              hipStream_t stream) {
    const float* x  = (const float*)d_in[0];
    const float* w1 = (const float*)d_in[1];
    const float* b1 = (const float*)d_in[2];
    const float* w2 = (const float*)d_in[3];
    const float* b2 = (const float*)d_in[4];
    float* out = (float*)d_out;

    float* ws  = (float*)d_ws;
    float* wt  = ws;                                   // NW floats (pad to 16384)
    float* sim = ws + 16384;                           // B*9*HW  floats
    float* h   = sim + (size_t)B * 9 * HW;             // B*16*HW floats

    transpose_w1_kernel<<<(NW + 255) / 256, 256, 0, stream>>>(w1, wt);

    int nthreads = B * HW / 2;   // 2 px per thread
    int nblocks = nthreads / 256; // 512
    sim_kernel<<<nblocks, 256, 0, stream>>>(x, sim);
    conv1_kernel<<<nblocks, 256, 0, stream>>>(x, sim, wt, b1, h);
    conv2_sample_kernel<<<nblocks, 256, 0, stream>>>(x, h, w2, b2, out);
}

// Round 3
// 357.042 us; speedup vs baseline: 1.1855x; 1.1404x over previous
//
#include <hip/hip_runtime.h>
#include <math.h>

#define B 4
#define C 64
#define H 256
#define W 256
#define CMID 16
#define CIN 73        // 64 + 9
#define HW (H*W)
#define NW (CIN*9*CMID)   // 10512 weights for conv1

// ---------------------------------------------------------------------------
// w1 (CMID, CIN, 3, 3) -> wt[(ci*9+k)*CMID + co]  (inner = 16 consecutive co)
// ---------------------------------------------------------------------------
__global__ void transpose_w1_kernel(const float* __restrict__ w1, float* __restrict__ wt) {
    int tid = blockIdx.x * blockDim.x + threadIdx.x;
    if (tid >= NW) return;
    int co = tid & (CMID - 1);
    int rest = tid >> 4;          // ci*9 + k
    int ci = rest / 9;
    int k = rest - ci * 9;
    wt[tid] = w1[(co * CIN + ci) * 9 + k];
}

// ---------------------------------------------------------------------------
// 3x4 stencil patch (rows y-1..y+1, cols x-1..x+2), zero-padded, 2 px/thread.
// ---------------------------------------------------------------------------
__device__ __forceinline__ void load_patch(const float* __restrict__ p,
                                           bool r0, bool r2, bool c0ok, bool c3ok,
                                           float v[3][4]) {
#pragma unroll
    for (int r = 0; r < 3; ++r) {
        bool rok = (r == 0) ? r0 : ((r == 2) ? r2 : true);
        const float* rp = p + (r - 1) * W;
        v[r][0] = (rok && c0ok) ? rp[-1] : 0.f;
        v[r][1] = rok ? rp[0] : 0.f;
        v[r][2] = rok ? rp[1] : 0.f;
        v[r][3] = (rok && c3ok) ? rp[2] : 0.f;
    }
}

// ---------------------------------------------------------------------------
// Local cosine similarity, 2 pixels/thread. sim layout (B, 9, H, W).
// ---------------------------------------------------------------------------
__global__ __launch_bounds__(256) void sim_kernel(const float* __restrict__ x,
                                                  float* __restrict__ sim) {
    int t = blockIdx.x * blockDim.x + threadIdx.x;
    int base = t * 2;
    int px = base & (W - 1);
    int py = (base >> 8) & (H - 1);
    int b  = base >> 16;
    int pix = py * W + px;

    const bool r0 = py > 0, r2 = py < H - 1;
    const bool c0ok = px > 0, c3ok = (px + 2) < W;

    const float* xb = x + (size_t)b * C * HW + pix;

    float csq0 = 0.f, csq1 = 0.f;
    float dot0[9], dot1[9], nsq0[9], nsq1[9];
#pragma unroll
    for (int k = 0; k < 9; ++k) { dot0[k] = dot1[k] = nsq0[k] = nsq1[k] = 0.f; }

#pragma unroll 2
    for (int ci = 0; ci < C; ++ci) {
        float v[3][4];
        load_patch(xb + (size_t)ci * HW, r0, r2, c0ok, c3ok, v);
        float cv0 = v[1][1], cv1 = v[1][2];
        csq0 = fmaf(cv0, cv0, csq0);
        csq1 = fmaf(cv1, cv1, csq1);
#pragma unroll
        for (int kr = 0; kr < 3; ++kr)
#pragma unroll
            for (int kc = 0; kc < 3; ++kc) {
                int k = kr * 3 + kc;
                if (k == 4) continue;
                float n0 = v[kr][kc], n1 = v[kr][kc + 1];
                dot0[k] = fmaf(cv0, n0, dot0[k]);
                nsq0[k] = fmaf(n0, n0, nsq0[k]);
                dot1[k] = fmaf(cv1, n1, dot1[k]);
                nsq1[k] = fmaf(n1, n1, nsq1[k]);
            }
    }
    dot0[4] = csq0; nsq0[4] = csq0;
    dot1[4] = csq1; nsq1[4] = csq1;

    float cn0 = sqrtf(csq0) + 1e-8f;
    float cn1 = sqrtf(csq1) + 1e-8f;
    float* so = sim + (size_t)b * 9 * HW + pix;
#pragma unroll
    for (int k = 0; k < 9; ++k) {
        float s0 = dot0[k] / (cn0 * (sqrtf(nsq0[k]) + 1e-8f));
        float s1 = dot1[k] / (cn1 * (sqrtf(nsq1[k]) + 1e-8f));
        *(float2*)(so + (size_t)k * HW) = make_float2(s0, s1);
    }
}

// ---------------------------------------------------------------------------
// Conv1 (73 -> 16, 3x3, pad 1) + leaky relu. 2 pixels/thread, weights in LDS.
// ---------------------------------------------------------------------------
__device__ __forceinline__ void conv1_accum(const float v[3][4], const float* __restrict__ wp,
                                            float acc0[CMID], float acc1[CMID]) {
#pragma unroll
    for (int kr = 0; kr < 3; ++kr)
#pragma unroll
        for (int kc = 0; kc < 3; ++kc) {
            float a0 = v[kr][kc], a1 = v[kr][kc + 1];
            const float4* w4 = (const float4*)(wp + (kr * 3 + kc) * CMID);
#pragma unroll
            for (int q = 0; q < 4; ++q) {
                float4 wv = w4[q];
                acc0[4 * q + 0] = fmaf(a0, wv.x, acc0[4 * q + 0]);
                acc0[4 * q + 1] = fmaf(a0, wv.y, acc0[4 * q + 1]);
                acc0[4 * q + 2] = fmaf(a0, wv.z, acc0[4 * q + 2]);
                acc0[4 * q + 3] = fmaf(a0, wv.w, acc0[4 * q + 3]);
                acc1[4 * q + 0] = fmaf(a1, wv.x, acc1[4 * q + 0]);
                acc1[4 * q + 1] = fmaf(a1, wv.y, acc1[4 * q + 1]);
                acc1[4 * q + 2] = fmaf(a1, wv.z, acc1[4 * q + 2]);
                acc1[4 * q + 3] = fmaf(a1, wv.w, acc1[4 * q + 3]);
            }
        }
}

__global__ __launch_bounds__(256) void conv1_kernel(const float* __restrict__ x,
                                                    const float* __restrict__ sim,
                                                    const float* __restrict__ wt,
                                                    const float* __restrict__ b1,
                                                    float* __restrict__ h) {
    __shared__ float4 lw4[NW / 4];
    {
        const float4* src = (const float4*)wt;
        for (int i = threadIdx.x; i < NW / 4; i += 256) lw4[i] = src[i];
    }
    __syncthreads();
    const float* lw = (const float*)lw4;

    int t = blockIdx.x * blockDim.x + threadIdx.x;
    int base = t * 2;
    int px = base & (W - 1);
    int py = (base >> 8) & (H - 1);
    int b  = base >> 16;
    int pix = py * W + px;

    const bool r0 = py > 0, r2 = py < H - 1;
    const bool c0ok = px > 0, c3ok = (px + 2) < W;

    const float* xb = x   + (size_t)b * C * HW + pix;
    const float* sb = sim + (size_t)b * 9 * HW + pix;

    float acc0[CMID], acc1[CMID];
#pragma unroll
    for (int co = 0; co < CMID; ++co) { acc0[co] = b1[co]; acc1[co] = b1[co]; }

#pragma unroll 2
    for (int ci = 0; ci < C; ++ci) {
        float v[3][4];
        load_patch(xb + (size_t)ci * HW, r0, r2, c0ok, c3ok, v);
        conv1_accum(v, lw + ci * 9 * CMID, acc0, acc1);
    }
#pragma unroll 2
    for (int ci = 0; ci < 9; ++ci) {
        float v[3][4];
        load_patch(sb + (size_t)ci * HW, r0, r2, c0ok, c3ok, v);
        conv1_accum(v, lw + (C + ci) * 9 * CMID, acc0, acc1);
    }

    float* ho = h + (size_t)b * CMID * HW + pix;
#pragma unroll
    for (int co = 0; co < CMID; ++co) {
        float v0 = acc0[co], v1 = acc1[co];
        v0 = v0 >= 0.f ? v0 : 0.2f * v0;
        v1 = v1 >= 0.f ? v1 : 0.2f * v1;
        *(float2*)(ho + (size_t)co * HW) = make_float2(v0, v1);
    }
}

// ---------------------------------------------------------------------------
// Offset kernel: conv2 (16->2) + tanh -> clamped sample coords (ix, iy).
// 1 pixel/thread for max parallelism. off_buf layout: float2 per pixel.
// ---------------------------------------------------------------------------
__global__ __launch_bounds__(256) void offset_kernel(const float* __restrict__ h,
                                                     const float* __restrict__ w2,
                                                     const float* __restrict__ b2,
                                                     float2* __restrict__ off_buf) {
    __shared__ float lw2[CMID * 9 * 2];
    for (int i = threadIdx.x; i < CMID * 9 * 2; i += 256) {
        int co = i & 1;
        int rest = i >> 1;      // ci*9 + k
        int ci = rest / 9;
        int k = rest - ci * 9;
        lw2[i] = w2[(co * CMID + ci) * 9 + k];
    }
    __syncthreads();

    int idx = blockIdx.x * blockDim.x + threadIdx.x;
    int px = idx & (W - 1);
    int py = (idx >> 8) & (H - 1);
    int b  = idx >> 16;
    int pix = py * W + px;

    const bool vy0 = py > 0, vy2 = py < H - 1;
    const bool vx0 = px > 0, vx2 = px < W - 1;
    const int off[9] = { -W - 1, -W, -W + 1, -1, 0, 1, W - 1, W, W + 1 };
    const bool valid[9] = { vy0 && vx0, vy0, vy0 && vx2,
                            vx0,        true, vx2,
                            vy2 && vx0, vy2, vy2 && vx2 };

    const float* hb = h + (size_t)b * CMID * HW + pix;
    float a0 = b2[0], a1 = b2[1];
#pragma unroll 2
    for (int ci = 0; ci < CMID; ++ci) {
        const float* p = hb + (size_t)ci * HW;
#pragma unroll
        for (int k = 0; k < 9; ++k) {
            float v = valid[k] ? p[off[k]] : 0.f;
            float2 wv = *(const float2*)(lw2 + (ci * 9 + k) * 2);
            a0 = fmaf(v, wv.x, a0);
            a1 = fmaf(v, wv.y, a1);
        }
    }

    float ix = (float)px + 0.1f * tanhf(a0) * (0.5f * (float)(W - 1));
    float iy = (float)py + 0.1f * tanhf(a1) * (0.5f * (float)(H - 1));
    ix = fminf(fmaxf(ix, 0.f), (float)(W - 1));
    iy = fminf(fmaxf(iy, 0.f), (float)(H - 1));
    off_buf[(size_t)b * HW + pix] = make_float2(ix, iy);
}

// ---------------------------------------------------------------------------
// Gather kernel: bilinear border sample. 2 px/thread, 16 channels per block-y.
// XCD swizzle: give each XCD a contiguous spatial slab for L2 locality.
// ---------------------------------------------------------------------------
__global__ __launch_bounds__(256) void sample_kernel(const float* __restrict__ x,
                                                     const float2* __restrict__ off_buf,
                                                     float* __restrict__ out) {
    // spatial block swizzle: blockIdx.x -> sb so that consecutive sb share an XCD
    int nb = gridDim.x;                 // 512 (power of two)
    int bid = blockIdx.x;
    int sb = (bid & 7) * (nb >> 3) + (bid >> 3);

    int t = sb * 256 + threadIdx.x;     // pixel-pair index
    int base = t * 2;
    int px = base & (W - 1);
    int py = (base >> 8) & (H - 1);
    int b  = base >> 16;
    int pix = py * W + px;

    // two pixels' coords in one 16B load
    float4 o = ((const float4*)off_buf)[t];
    float ix0 = o.x, iy0 = o.y, ix1 = o.z, iy1 = o.w;

    float x0f0 = floorf(ix0), y0f0 = floorf(iy0);
    float x0f1 = floorf(ix1), y0f1 = floorf(iy1);
    float wx0 = ix0 - x0f0, wy0 = iy0 - y0f0;
    float wx1 = ix1 - x0f1, wy1 = iy1 - y0f1;
    int x00 = (int)x0f0, y00 = (int)y0f0;
    int x01 = (int)x0f1, y01 = (int)y0f1;
    int x10 = min(x00 + 1, W - 1), y10 = min(y00 + 1, H - 1);
    int x11 = min(x01 + 1, W - 1), y11 = min(y01 + 1, H - 1);

    int i00_0 = y00 * W + x00, i01_0 = y00 * W + x10;
    int i10_0 = y10 * W + x00, i11_0 = y10 * W + x10;
    int i00_1 = y01 * W + x01, i01_1 = y01 * W + x11;
    int i10_1 = y11 * W + x01, i11_1 = y11 * W + x11;

    int c0 = blockIdx.y * (C / 4);      // 16 channels per y-block
    const float* xb = x + ((size_t)b * C + c0) * HW;
    float* ob = out + ((size_t)b * C + c0) * HW + pix;

#pragma unroll 2
    for (int c = 0; c < C / 4; ++c) {
        const float* img = xb + (size_t)c * HW;
        float v00 = img[i00_0], v01 = img[i01_0], v10 = img[i10_0], v11 = img[i11_0];
        float top0 = fmaf(wx0, v01 - v00, v00);
        float bot0 = fmaf(wx0, v11 - v10, v10);
        float o0 = fmaf(wy0, bot0 - top0, top0);
        float u00 = img[i00_1], u01 = img[i01_1], u10 = img[i10_1], u11 = img[i11_1];
        float top1 = fmaf(wx1, u01 - u00, u00);
        float bot1 = fmaf(wx1, u11 - u10, u10);
        float o1 = fmaf(wy1, bot1 - top1, top1);
        *(float2*)(ob + (size_t)c * HW) = make_float2(o0, o1);
    }
}

// ---------------------------------------------------------------------------
extern "C" void kernel_launch(void* const* d_in, const int* in_sizes, int n_in,
                              void* d_out, int out_size, void* d_ws, size_t ws_size,
                              hipStream_t stream) {
    const float* x  = (const float*)d_in[0];
    const float* w1 = (const float*)d_in[1];
    const float* b1 = (const float*)d_in[2];
    const float* w2 = (const float*)d_in[3];
    const float* b2 = (const float*)d_in[4];
    float* out = (float*)d_out;

    float* ws  = (float*)d_ws;
    float* wt  = ws;                                   // 16384 floats
    float* sim = ws + 16384;                           // B*9*HW floats
    float* h   = sim + (size_t)B * 9 * HW;             // B*16*HW floats
    float2* off_buf = (float2*)(h + (size_t)B * CMID * HW);  // B*HW float2

    transpose_w1_kernel<<<(NW + 255) / 256, 256, 0, stream>>>(w1, wt);

    int npair = B * HW / 2;              // 2 px per thread
    int nblocks = npair / 256;           // 512
    sim_kernel<<<nblocks, 256, 0, stream>>>(x, sim);
    conv1_kernel<<<nblocks, 256, 0, stream>>>(x, sim, wt, b1, h);
    offset_kernel<<<B * HW / 256, 256, 0, stream>>>(h, w2, b2, off_buf);
    sample_kernel<<<dim3(nblocks, 4), 256, 0, stream>>>(x, off_buf, out);
}

// Round 4
// 283.496 us; speedup vs baseline: 1.4931x; 1.2594x over previous
//
#include <hip/hip_runtime.h>
#include <math.h>

#define B 4
#define C 64
#define H 256
#define W 256
#define CMID 16
#define CIN 73        // 64 + 9
#define HW (H*W)
#define NW (CIN*9*CMID)   // 10512 conv1 weights
#define XS_STRIDE 260     // LDS row stride: [0]=left halo, [1..256]=x, [257]=right halo

// ---------------------------------------------------------------------------
// w1 (CMID, CIN, 3, 3) -> wt[(ci*9+k)*CMID + co]
// ---------------------------------------------------------------------------
__global__ void transpose_w1_kernel(const float* __restrict__ w1, float* __restrict__ wt) {
    int tid = blockIdx.x * blockDim.x + threadIdx.x;
    if (tid >= NW) return;
    int co = tid & (CMID - 1);
    int rest = tid >> 4;          // ci*9 + k
    int ci = rest / 9;
    int k = rest - ci * 9;
    wt[tid] = w1[(co * CIN + ci) * 9 + k];
}

// ---------------------------------------------------------------------------
// Strip decode shared by sim/conv1/offset:
// 512 blocks; block = (b, 2-row strip). 256 threads: rl = tid>>7 (strip row),
// k = tid&127 (pixel pair), px = 2k. Stage duty: wave w stages row w of 4.
// ---------------------------------------------------------------------------
__device__ __forceinline__ void read_patch_lds(const float* __restrict__ xsbuf,
                                               int rl, int px, float v[3][4]) {
    const float* pb = xsbuf + rl * XS_STRIDE + px;   // element (rl+r)*260 + px + c
#pragma unroll
    for (int r = 0; r < 3; ++r) {
        float2 p0 = *(const float2*)(pb + r * XS_STRIDE);
        float2 p1 = *(const float2*)(pb + r * XS_STRIDE + 2);
        v[r][0] = p0.x; v[r][1] = p0.y; v[r][2] = p1.x; v[r][3] = p1.y;
    }
}

// ---------------------------------------------------------------------------
// Local cosine similarity. Double-buffered LDS x staging.
// ---------------------------------------------------------------------------
__global__ __launch_bounds__(256) void sim_kernel(const float* __restrict__ x,
                                                  float* __restrict__ sim) {
    __shared__ float xs[2][4 * XS_STRIDE];
    int bid = blockIdx.x;
    int b  = bid >> 7;
    int y0 = (bid & 127) << 1;
    int tid = threadIdx.x;
    int srow = tid >> 6;              // stage row 0..3 (wave-uniform)
    int sx4  = (tid & 63) << 2;
    int rl = tid >> 7;
    int px = (tid & 127) << 1;
    int y  = y0 + rl;

    int grow = y0 - 1 + srow;
    bool gvalid = (grow >= 0) && (grow < H);
    const float* gsrc = x + (size_t)b * C * HW + (size_t)grow * W + sx4;

    if (tid < 16) {   // zero halo columns in both buffers, all 4 rows
        int bu = tid >> 3, r = (tid >> 1) & 3, e = (tid & 1) ? 257 : 0;
        xs[bu][r * XS_STRIDE + e] = 0.f;
    }

    float dot0[9], dot1[9], nsq0[9], nsq1[9];
    float csq0 = 0.f, csq1 = 0.f;
#pragma unroll
    for (int i = 0; i < 9; ++i) { dot0[i] = dot1[i] = nsq0[i] = nsq1[i] = 0.f; }

    float4 r4 = make_float4(0.f, 0.f, 0.f, 0.f);
    if (gvalid) r4 = *(const float4*)gsrc;

    int cur = 0;
#pragma unroll 1
    for (int ci = 0; ci < C; ++ci) {
        float* dst = &xs[cur][srow * XS_STRIDE + 1 + sx4];
        dst[0] = r4.x; dst[1] = r4.y; dst[2] = r4.z; dst[3] = r4.w;
        __syncthreads();
        if (ci + 1 < C) {
            r4 = make_float4(0.f, 0.f, 0.f, 0.f);
            if (gvalid) r4 = *(const float4*)(gsrc + (size_t)(ci + 1) * HW);
        }
        float v[3][4];
        read_patch_lds(xs[cur], rl, px, v);
        float cv0 = v[1][1], cv1 = v[1][2];
        csq0 = fmaf(cv0, cv0, csq0);
        csq1 = fmaf(cv1, cv1, csq1);
#pragma unroll
        for (int kr = 0; kr < 3; ++kr)
#pragma unroll
            for (int kc = 0; kc < 3; ++kc) {
                int kk = kr * 3 + kc;
                if (kk == 4) continue;
                float n0 = v[kr][kc], n1 = v[kr][kc + 1];
                dot0[kk] = fmaf(cv0, n0, dot0[kk]);
                nsq0[kk] = fmaf(n0, n0, nsq0[kk]);
                dot1[kk] = fmaf(cv1, n1, dot1[kk]);
                nsq1[kk] = fmaf(n1, n1, nsq1[kk]);
            }
        cur ^= 1;
    }
    dot0[4] = csq0; nsq0[4] = csq0;
    dot1[4] = csq1; nsq1[4] = csq1;

    float cn0 = sqrtf(csq0) + 1e-8f;
    float cn1 = sqrtf(csq1) + 1e-8f;
    float* so = sim + (size_t)b * 9 * HW + (size_t)y * W + px;
#pragma unroll
    for (int kk = 0; kk < 9; ++kk) {
        float s0 = dot0[kk] / (cn0 * (sqrtf(nsq0[kk]) + 1e-8f));
        float s1 = dot1[kk] / (cn1 * (sqrtf(nsq1[kk]) + 1e-8f));
        *(float2*)(so + (size_t)kk * HW) = make_float2(s0, s1);
    }
}

// ---------------------------------------------------------------------------
// Conv1 (73->16) + leaky. Weights in LDS, x/sim staged double-buffered.
// ---------------------------------------------------------------------------
__global__ __launch_bounds__(256) void conv1_kernel(const float* __restrict__ x,
                                                    const float* __restrict__ sim,
                                                    const float* __restrict__ wt,
                                                    const float* __restrict__ b1,
                                                    float* __restrict__ h) {
    __shared__ float lw[NW];                  // 42048 B
    __shared__ float xs[2][4 * XS_STRIDE];    // 8320 B

    int tid = threadIdx.x;
    for (int j = tid; j < NW / 4; j += 256)
        ((float4*)lw)[j] = ((const float4*)wt)[j];

    int bid = blockIdx.x;
    int b  = bid >> 7;
    int y0 = (bid & 127) << 1;
    int srow = tid >> 6;
    int sx4  = (tid & 63) << 2;
    int rl = tid >> 7;
    int px = (tid & 127) << 1;
    int y  = y0 + rl;

    int grow = y0 - 1 + srow;
    bool gvalid = (grow >= 0) && (grow < H);
    const float* gx = x   + (size_t)b * C * HW + (size_t)grow * W + sx4;
    const float* gs = sim + (size_t)b * 9 * HW + (size_t)grow * W + sx4;

    if (tid < 16) {
        int bu = tid >> 3, r = (tid >> 1) & 3, e = (tid & 1) ? 257 : 0;
        xs[bu][r * XS_STRIDE + e] = 0.f;
    }

    float acc0[CMID], acc1[CMID];
#pragma unroll
    for (int co = 0; co < CMID; ++co) { acc0[co] = b1[co]; acc1[co] = b1[co]; }

    float4 r4 = make_float4(0.f, 0.f, 0.f, 0.f);
    if (gvalid) r4 = *(const float4*)gx;

    int cur = 0;
#pragma unroll 1
    for (int ci = 0; ci < CIN; ++ci) {
        float* dst = &xs[cur][srow * XS_STRIDE + 1 + sx4];
        dst[0] = r4.x; dst[1] = r4.y; dst[2] = r4.z; dst[3] = r4.w;
        __syncthreads();
        if (ci + 1 < CIN) {
            const float* src = (ci + 1 < C) ? (gx + (size_t)(ci + 1) * HW)
                                            : (gs + (size_t)(ci + 1 - C) * HW);
            r4 = make_float4(0.f, 0.f, 0.f, 0.f);
            if (gvalid) r4 = *(const float4*)src;
        }
        float v[3][4];
        read_patch_lds(xs[cur], rl, px, v);
        const float* wp = lw + ci * 144;
#pragma unroll
        for (int kr = 0; kr < 3; ++kr)
#pragma unroll
            for (int kc = 0; kc < 3; ++kc) {
                float a0 = v[kr][kc], a1 = v[kr][kc + 1];
                const float4* w4 = (const float4*)(wp + (kr * 3 + kc) * CMID);
#pragma unroll
                for (int q = 0; q < 4; ++q) {
                    float4 wv = w4[q];
                    acc0[4 * q + 0] = fmaf(a0, wv.x, acc0[4 * q + 0]);
                    acc0[4 * q + 1] = fmaf(a0, wv.y, acc0[4 * q + 1]);
                    acc0[4 * q + 2] = fmaf(a0, wv.z, acc0[4 * q + 2]);
                    acc0[4 * q + 3] = fmaf(a0, wv.w, acc0[4 * q + 3]);
                    acc1[4 * q + 0] = fmaf(a1, wv.x, acc1[4 * q + 0]);
                    acc1[4 * q + 1] = fmaf(a1, wv.y, acc1[4 * q + 1]);
                    acc1[4 * q + 2] = fmaf(a1, wv.z, acc1[4 * q + 2]);
                    acc1[4 * q + 3] = fmaf(a1, wv.w, acc1[4 * q + 3]);
                }
            }
        cur ^= 1;
    }

    float* ho = h + (size_t)b * CMID * HW + (size_t)y * W + px;
#pragma unroll
    for (int co = 0; co < CMID; ++co) {
        float v0 = acc0[co], v1 = acc1[co];
        v0 = v0 >= 0.f ? v0 : 0.2f * v0;
        v1 = v1 >= 0.f ? v1 : 0.2f * v1;
        *(float2*)(ho + (size_t)co * HW) = make_float2(v0, v1);
    }
}

// ---------------------------------------------------------------------------
// Conv2 (16->2) + tanh -> clamped sample coords. Same strip staging on h.
// off_buf: float2 (ix,iy) per pixel.
// ---------------------------------------------------------------------------
__global__ __launch_bounds__(256) void offset_kernel(const float* __restrict__ h,
                                                     const float* __restrict__ w2,
                                                     const float* __restrict__ b2,
                                                     float2* __restrict__ off_buf) {
    __shared__ float lw2[CMID * 9 * 2];
    __shared__ float xs[2][4 * XS_STRIDE];

    int tid = threadIdx.x;
    for (int i = tid; i < CMID * 9 * 2; i += 256) {
        int co = i & 1;
        int rest = i >> 1;
        int ci = rest / 9;
        int kk = rest - ci * 9;
        lw2[i] = w2[(co * CMID + ci) * 9 + kk];
    }

    int bid = blockIdx.x;
    int b  = bid >> 7;
    int y0 = (bid & 127) << 1;
    int srow = tid >> 6;
    int sx4  = (tid & 63) << 2;
    int rl = tid >> 7;
    int px = (tid & 127) << 1;
    int y  = y0 + rl;

    int grow = y0 - 1 + srow;
    bool gvalid = (grow >= 0) && (grow < H);
    const float* gh = h + (size_t)b * CMID * HW + (size_t)grow * W + sx4;

    if (tid < 16) {
        int bu = tid >> 3, r = (tid >> 1) & 3, e = (tid & 1) ? 257 : 0;
        xs[bu][r * XS_STRIDE + e] = 0.f;
    }

    float s0x = b2[0], s0y = b2[1], s1x = b2[0], s1y = b2[1];

    float4 r4 = make_float4(0.f, 0.f, 0.f, 0.f);
    if (gvalid) r4 = *(const float4*)gh;

    int cur = 0;
#pragma unroll 1
    for (int ci = 0; ci < CMID; ++ci) {
        float* dst = &xs[cur][srow * XS_STRIDE + 1 + sx4];
        dst[0] = r4.x; dst[1] = r4.y; dst[2] = r4.z; dst[3] = r4.w;
        __syncthreads();
        if (ci + 1 < CMID) {
            r4 = make_float4(0.f, 0.f, 0.f, 0.f);
            if (gvalid) r4 = *(const float4*)(gh + (size_t)(ci + 1) * HW);
        }
        float v[3][4];
        read_patch_lds(xs[cur], rl, px, v);
#pragma unroll
        for (int kr = 0; kr < 3; ++kr)
#pragma unroll
            for (int kc = 0; kc < 3; ++kc) {
                float2 wv = *(const float2*)(lw2 + (ci * 9 + kr * 3 + kc) * 2);
                s0x = fmaf(v[kr][kc],     wv.x, s0x);
                s0y = fmaf(v[kr][kc],     wv.y, s0y);
                s1x = fmaf(v[kr][kc + 1], wv.x, s1x);
                s1y = fmaf(v[kr][kc + 1], wv.y, s1y);
            }
        cur ^= 1;
    }

    float ix0 = (float)px       + 0.1f * tanhf(s0x) * (0.5f * (float)(W - 1));
    float iy0 = (float)y        + 0.1f * tanhf(s0y) * (0.5f * (float)(H - 1));
    float ix1 = (float)(px + 1) + 0.1f * tanhf(s1x) * (0.5f * (float)(W - 1));
    float iy1 = (float)y        + 0.1f * tanhf(s1y) * (0.5f * (float)(H - 1));
    ix0 = fminf(fmaxf(ix0, 0.f), (float)(W - 1));
    iy0 = fminf(fmaxf(iy0, 0.f), (float)(H - 1));
    ix1 = fminf(fmaxf(ix1, 0.f), (float)(W - 1));
    iy1 = fminf(fmaxf(iy1, 0.f), (float)(H - 1));

    float4* op = (float4*)(off_buf + (size_t)b * HW + (size_t)y * W + px);
    *op = make_float4(ix0, iy0, ix1, iy1);
}

// ---------------------------------------------------------------------------
// Bilinear border sample via LDS row cache. Tile = 8 rows x 256 cols; block
// stages the 35 source rows coalesced, gathers from LDS. 4 channels/block.
// ---------------------------------------------------------------------------
#define SROWS 35
__global__ __launch_bounds__(256) void sample_kernel(const float* __restrict__ x,
                                                     const float2* __restrict__ off_buf,
                                                     float* __restrict__ out) {
    __shared__ float xs[SROWS * 256];    // 35840 B

    int bid = blockIdx.x;                        // 0..127 tiles
    int sb = (bid & 7) * 16 + (bid >> 3);        // XCD-contiguous 16-tile bands
    int b  = sb >> 5;
    int ty = sb & 31;
    int cg = blockIdx.y;                         // 0..15 channel groups (4 ch)
    int tid = threadIdx.x;                       // column

    int ybase = ty << 3;
    int lo = ybase - 13;

    int a00[8], a01[8], a10[8], a11[8];
    float wx[8], wy[8];
    const float2* ob2 = off_buf + (size_t)b * HW + (size_t)ybase * W + tid;
#pragma unroll
    for (int r = 0; r < 8; ++r) {
        float2 o = ob2[r * W];
        float xf = floorf(o.x), yf = floorf(o.y);
        wx[r] = o.x - xf; wy[r] = o.y - yf;
        int x0 = (int)xf, yy0 = (int)yf;
        int x1 = min(x0 + 1, W - 1), yy1 = min(yy0 + 1, H - 1);
        int r0 = (yy0 - lo) << 8, r1 = (yy1 - lo) << 8;
        a00[r] = r0 + x0; a01[r] = r0 + x1;
        a10[r] = r1 + x0; a11[r] = r1 + x1;
    }

    const float* xb = x + ((size_t)b * C + cg * 4) * HW;
    float* outb = out + ((size_t)b * C + cg * 4) * HW + (size_t)ybase * W + tid;

#pragma unroll 1
    for (int c = 0; c < 4; ++c) {
        __syncthreads();
        const float* src = xb + (size_t)c * HW;
        for (int j = tid; j < SROWS * 64; j += 256) {
            int row = j >> 6, x4 = (j & 63) << 2;
            int grw = min(max(lo + row, 0), H - 1);
            *(float4*)&xs[(row << 8) + x4] = *(const float4*)(src + (size_t)grw * W + x4);
        }
        __syncthreads();
        float* oc = outb + (size_t)c * HW;
#pragma unroll
        for (int r = 0; r < 8; ++r) {
            float v00 = xs[a00[r]], v01 = xs[a01[r]];
            float v10 = xs[a10[r]], v11 = xs[a11[r]];
            float top = fmaf(wx[r], v01 - v00, v00);
            float bot = fmaf(wx[r], v11 - v10, v10);
            oc[r * W] = fmaf(wy[r], bot - top, top);
        }
    }
}

// ---------------------------------------------------------------------------
extern "C" void kernel_launch(void* const* d_in, const int* in_sizes, int n_in,
                              void* d_out, int out_size, void* d_ws, size_t ws_size,
                              hipStream_t stream) {
    const float* x  = (const float*)d_in[0];
    const float* w1 = (const float*)d_in[1];
    const float* b1 = (const float*)d_in[2];
    const float* w2 = (const float*)d_in[3];
    const float* b2 = (const float*)d_in[4];
    float* out = (float*)d_out;

    float* ws  = (float*)d_ws;
    float* wt  = ws;                                         // 16384 floats
    float* sim = ws + 16384;                                 // B*9*HW
    float* h   = sim + (size_t)B * 9 * HW;                   // B*16*HW
    float2* off_buf = (float2*)(h + (size_t)B * CMID * HW);  // B*HW float2

    transpose_w1_kernel<<<(NW + 255) / 256, 256, 0, stream>>>(w1, wt);

    sim_kernel<<<512, 256, 0, stream>>>(x, sim);
    conv1_kernel<<<512, 256, 0, stream>>>(x, sim, wt, b1, h);
    offset_kernel<<<512, 256, 0, stream>>>(h, w2, b2, off_buf);
    sample_kernel<<<dim3(128, 16), 256, 0, stream>>>(x, off_buf, out);
}

// Round 5
// 262.926 us; speedup vs baseline: 1.6099x; 1.0782x over previous
//
#include <hip/hip_runtime.h>
#include <math.h>

#define B 4
#define C 64
#define H 256
#define W 256
#define CMID 16
#define CIN 73        // 64 + 9
#define HW (H*W)
#define NW (CIN*9*CMID)   // 10512 conv1 weights
#define XS_STRIDE 260     // LDS row stride: [0]=left halo, [1..256]=x, [257]=right halo

// ---------------------------------------------------------------------------
// w1 (CMID, CIN, 3, 3) -> wt[(ci*9+k)*CMID + co]
// ---------------------------------------------------------------------------
__global__ void transpose_w1_kernel(const float* __restrict__ w1, float* __restrict__ wt) {
    int tid = blockIdx.x * blockDim.x + threadIdx.x;
    if (tid >= NW) return;
    int co = tid & (CMID - 1);
    int rest = tid >> 4;          // ci*9 + k
    int ci = rest / 9;
    int k = rest - ci * 9;
    wt[tid] = w1[(co * CIN + ci) * 9 + k];
}

// ---------------------------------------------------------------------------
// Strip decode shared by sim/conv1/offset:
// 512 blocks; block = (b, 2-row strip). 256 threads: rl = tid>>7 (strip row),
// k = tid&127 (pixel pair), px = 2k. Stage duty: wave w stages row w of 4.
// ---------------------------------------------------------------------------
__device__ __forceinline__ void read_patch_lds(const float* __restrict__ xsbuf,
                                               int rl, int px, float v[3][4]) {
    const float* pb = xsbuf + rl * XS_STRIDE + px;
#pragma unroll
    for (int r = 0; r < 3; ++r) {
        float2 p0 = *(const float2*)(pb + r * XS_STRIDE);
        float2 p1 = *(const float2*)(pb + r * XS_STRIDE + 2);
        v[r][0] = p0.x; v[r][1] = p0.y; v[r][2] = p1.x; v[r][3] = p1.y;
    }
}

// ---------------------------------------------------------------------------
// Local cosine similarity. Double-buffered LDS x staging. (unchanged)
// ---------------------------------------------------------------------------
__global__ __launch_bounds__(256) void sim_kernel(const float* __restrict__ x,
                                                  float* __restrict__ sim) {
    __shared__ float xs[2][4 * XS_STRIDE];
    int bid = blockIdx.x;
    int b  = bid >> 7;
    int y0 = (bid & 127) << 1;
    int tid = threadIdx.x;
    int srow = tid >> 6;              // stage row 0..3 (wave-uniform)
    int sx4  = (tid & 63) << 2;
    int rl = tid >> 7;
    int px = (tid & 127) << 1;
    int y  = y0 + rl;

    int grow = y0 - 1 + srow;
    bool gvalid = (grow >= 0) && (grow < H);
    const float* gsrc = x + (size_t)b * C * HW + (size_t)grow * W + sx4;

    if (tid < 16) {   // zero halo columns in both buffers, all 4 rows
        int bu = tid >> 3, r = (tid >> 1) & 3, e = (tid & 1) ? 257 : 0;
        xs[bu][r * XS_STRIDE + e] = 0.f;
    }

    float dot0[9], dot1[9], nsq0[9], nsq1[9];
    float csq0 = 0.f, csq1 = 0.f;
#pragma unroll
    for (int i = 0; i < 9; ++i) { dot0[i] = dot1[i] = nsq0[i] = nsq1[i] = 0.f; }

    float4 r4 = make_float4(0.f, 0.f, 0.f, 0.f);
    if (gvalid) r4 = *(const float4*)gsrc;

    int cur = 0;
#pragma unroll 1
    for (int ci = 0; ci < C; ++ci) {
        float* dst = &xs[cur][srow * XS_STRIDE + 1 + sx4];
        dst[0] = r4.x; dst[1] = r4.y; dst[2] = r4.z; dst[3] = r4.w;
        __syncthreads();
        if (ci + 1 < C) {
            r4 = make_float4(0.f, 0.f, 0.f, 0.f);
            if (gvalid) r4 = *(const float4*)(gsrc + (size_t)(ci + 1) * HW);
        }
        float v[3][4];
        read_patch_lds(xs[cur], rl, px, v);
        float cv0 = v[1][1], cv1 = v[1][2];
        csq0 = fmaf(cv0, cv0, csq0);
        csq1 = fmaf(cv1, cv1, csq1);
#pragma unroll
        for (int kr = 0; kr < 3; ++kr)
#pragma unroll
            for (int kc = 0; kc < 3; ++kc) {
                int kk = kr * 3 + kc;
                if (kk == 4) continue;
                float n0 = v[kr][kc], n1 = v[kr][kc + 1];
                dot0[kk] = fmaf(cv0, n0, dot0[kk]);
                nsq0[kk] = fmaf(n0, n0, nsq0[kk]);
                dot1[kk] = fmaf(cv1, n1, dot1[kk]);
                nsq1[kk] = fmaf(n1, n1, nsq1[kk]);
            }
        cur ^= 1;
    }
    dot0[4] = csq0; nsq0[4] = csq0;
    dot1[4] = csq1; nsq1[4] = csq1;

    float cn0 = sqrtf(csq0) + 1e-8f;
    float cn1 = sqrtf(csq1) + 1e-8f;
    float* so = sim + (size_t)b * 9 * HW + (size_t)y * W + px;
#pragma unroll
    for (int kk = 0; kk < 9; ++kk) {
        float s0 = dot0[kk] / (cn0 * (sqrtf(nsq0[kk]) + 1e-8f));
        float s1 = dot1[kk] / (cn1 * (sqrtf(nsq1[kk]) + 1e-8f));
        *(float2*)(so + (size_t)kk * HW) = make_float2(s0, s1);
    }
}

// ---------------------------------------------------------------------------
// Conv1 (73->16) + leaky. Activations staged in LDS (2 channels per barrier);
// weights read at WAVE-UNIFORM global addresses -> scalar s_load pipe.
// ---------------------------------------------------------------------------
__device__ __forceinline__ void conv1_chan(const float* __restrict__ xsbuf,
                                           int rl, int px,
                                           const float* __restrict__ wp,  // uniform!
                                           float acc0[CMID], float acc1[CMID]) {
    float v[3][4];
    read_patch_lds(xsbuf, rl, px, v);
#pragma unroll
    for (int kr = 0; kr < 3; ++kr)
#pragma unroll
        for (int kc = 0; kc < 3; ++kc) {
            float a0 = v[kr][kc], a1 = v[kr][kc + 1];
            const float* w = wp + (kr * 3 + kc) * CMID;
#pragma unroll
            for (int co = 0; co < CMID; ++co) {
                float wv = w[co];                 // uniform -> SGPR operand
                acc0[co] = fmaf(a0, wv, acc0[co]);
                acc1[co] = fmaf(a1, wv, acc1[co]);
            }
        }
}

__global__ __launch_bounds__(256) void conv1_kernel(const float* __restrict__ x,
                                                    const float* __restrict__ sim,
                                                    const float* __restrict__ wt,
                                                    const float* __restrict__ b1,
                                                    float* __restrict__ h) {
    __shared__ float xs[2][2][4 * XS_STRIDE];   // [buf][ch][row*stride] = 16640 B

    int tid = threadIdx.x;
    int bid = blockIdx.x;
    int b  = bid >> 7;
    int y0 = (bid & 127) << 1;
    int srow = tid >> 6;
    int sx4  = (tid & 63) << 2;
    int rl = tid >> 7;
    int px = (tid & 127) << 1;
    int y  = y0 + rl;

    int grow = y0 - 1 + srow;
    bool gvalid = (grow >= 0) && (grow < H);
    const float* gx = x   + (size_t)b * C * HW + (size_t)grow * W + sx4;
    const float* gs = sim + (size_t)b * 9 * HW + (size_t)grow * W + sx4;

    if (tid < 32) {   // zero halo cols: 2 bufs x 2 ch x 4 rows x {0,257}
        int bu = tid >> 4, ch = (tid >> 3) & 1, r = (tid >> 1) & 3;
        int e = (tid & 1) ? 257 : 0;
        xs[bu][ch][r * XS_STRIDE + e] = 0.f;
    }

    float acc0[CMID], acc1[CMID];
#pragma unroll
    for (int co = 0; co < CMID; ++co) { acc0[co] = b1[co]; acc1[co] = b1[co]; }

    // prefetch channels 0,1
    float4 p0 = make_float4(0.f, 0.f, 0.f, 0.f), p1 = p0;
    if (gvalid) {
        p0 = *(const float4*)gx;
        p1 = *(const float4*)(gx + HW);
    }

    int cur = 0;
#pragma unroll 1
    for (int cc = 0; cc < CIN; cc += 2) {
        float* d0 = &xs[cur][0][srow * XS_STRIDE + 1 + sx4];
        float* d1 = &xs[cur][1][srow * XS_STRIDE + 1 + sx4];
        d0[0] = p0.x; d0[1] = p0.y; d0[2] = p0.z; d0[3] = p0.w;
        d1[0] = p1.x; d1[1] = p1.y; d1[2] = p1.z; d1[3] = p1.w;
        __syncthreads();

        // prefetch cc+2, cc+3
        if (cc + 2 < CIN && gvalid) {
            int ci = cc + 2;
            p0 = (ci < C) ? *(const float4*)(gx + (size_t)ci * HW)
                          : *(const float4*)(gs + (size_t)(ci - C) * HW);
        }
        if (cc + 3 < CIN && gvalid) {
            int ci = cc + 3;
            p1 = (ci < C) ? *(const float4*)(gx + (size_t)ci * HW)
                          : *(const float4*)(gs + (size_t)(ci - C) * HW);
        }

        conv1_chan(xs[cur][0], rl, px, wt + cc * 144, acc0, acc1);
        if (cc + 1 < CIN)
            conv1_chan(xs[cur][1], rl, px, wt + (cc + 1) * 144, acc0, acc1);
        cur ^= 1;
    }

    float* ho = h + (size_t)b * CMID * HW + (size_t)y * W + px;
#pragma unroll
    for (int co = 0; co < CMID; ++co) {
        float v0 = acc0[co], v1 = acc1[co];
        v0 = v0 >= 0.f ? v0 : 0.2f * v0;
        v1 = v1 >= 0.f ? v1 : 0.2f * v1;
        *(float2*)(ho + (size_t)co * HW) = make_float2(v0, v1);
    }
}

// ---------------------------------------------------------------------------
// Conv2 (16->2) + tanh -> clamped sample coords. (unchanged)
// ---------------------------------------------------------------------------
__global__ __launch_bounds__(256) void offset_kernel(const float* __restrict__ h,
                                                     const float* __restrict__ w2,
                                                     const float* __restrict__ b2,
                                                     float2* __restrict__ off_buf) {
    __shared__ float lw2[CMID * 9 * 2];
    __shared__ float xs[2][4 * XS_STRIDE];

    int tid = threadIdx.x;
    for (int i = tid; i < CMID * 9 * 2; i += 256) {
        int co = i & 1;
        int rest = i >> 1;
        int ci = rest / 9;
        int kk = rest - ci * 9;
        lw2[i] = w2[(co * CMID + ci) * 9 + kk];
    }

    int bid = blockIdx.x;
    int b  = bid >> 7;
    int y0 = (bid & 127) << 1;
    int srow = tid >> 6;
    int sx4  = (tid & 63) << 2;
    int rl = tid >> 7;
    int px = (tid & 127) << 1;
    int y  = y0 + rl;

    int grow = y0 - 1 + srow;
    bool gvalid = (grow >= 0) && (grow < H);
    const float* gh = h + (size_t)b * CMID * HW + (size_t)grow * W + sx4;

    if (tid < 16) {
        int bu = tid >> 3, r = (tid >> 1) & 3, e = (tid & 1) ? 257 : 0;
        xs[bu][r * XS_STRIDE + e] = 0.f;
    }

    float s0x = b2[0], s0y = b2[1], s1x = b2[0], s1y = b2[1];

    float4 r4 = make_float4(0.f, 0.f, 0.f, 0.f);
    if (gvalid) r4 = *(const float4*)gh;

    int cur = 0;
#pragma unroll 1
    for (int ci = 0; ci < CMID; ++ci) {
        float* dst = &xs[cur][srow * XS_STRIDE + 1 + sx4];
        dst[0] = r4.x; dst[1] = r4.y; dst[2] = r4.z; dst[3] = r4.w;
        __syncthreads();
        if (ci + 1 < CMID) {
            r4 = make_float4(0.f, 0.f, 0.f, 0.f);
            if (gvalid) r4 = *(const float4*)(gh + (size_t)(ci + 1) * HW);
        }
        float v[3][4];
        read_patch_lds(xs[cur], rl, px, v);
#pragma unroll
        for (int kr = 0; kr < 3; ++kr)
#pragma unroll
            for (int kc = 0; kc < 3; ++kc) {
                float2 wv = *(const float2*)(lw2 + (ci * 9 + kr * 3 + kc) * 2);
                s0x = fmaf(v[kr][kc],     wv.x, s0x);
                s0y = fmaf(v[kr][kc],     wv.y, s0y);
                s1x = fmaf(v[kr][kc + 1], wv.x, s1x);
                s1y = fmaf(v[kr][kc + 1], wv.y, s1y);
            }
        cur ^= 1;
    }

    float ix0 = (float)px       + 0.1f * tanhf(s0x) * (0.5f * (float)(W - 1));
    float iy0 = (float)y        + 0.1f * tanhf(s0y) * (0.5f * (float)(H - 1));
    float ix1 = (float)(px + 1) + 0.1f * tanhf(s1x) * (0.5f * (float)(W - 1));
    float iy1 = (float)y        + 0.1f * tanhf(s1y) * (0.5f * (float)(H - 1));
    ix0 = fminf(fmaxf(ix0, 0.f), (float)(W - 1));
    iy0 = fminf(fmaxf(iy0, 0.f), (float)(H - 1));
    ix1 = fminf(fmaxf(ix1, 0.f), (float)(W - 1));
    iy1 = fminf(fmaxf(iy1, 0.f), (float)(H - 1));

    float4* op = (float4*)(off_buf + (size_t)b * HW + (size_t)y * W + px);
    *op = make_float4(ix0, iy0, ix1, iy1);
}

// ---------------------------------------------------------------------------
// Bilinear border sample via LDS row cache. (unchanged)
// ---------------------------------------------------------------------------
#define SROWS 35
__global__ __launch_bounds__(256) void sample_kernel(const float* __restrict__ x,
                                                     const float2* __restrict__ off_buf,
                                                     float* __restrict__ out) {
    __shared__ float xs[SROWS * 256];    // 35840 B

    int bid = blockIdx.x;                        // 0..127 tiles
    int sb = (bid & 7) * 16 + (bid >> 3);        // XCD-contiguous 16-tile bands
    int b  = sb >> 5;
    int ty = sb & 31;
    int cg = blockIdx.y;                         // 0..15 channel groups (4 ch)
    int tid = threadIdx.x;                       // column

    int ybase = ty << 3;
    int lo = ybase - 13;

    int a00[8], a01[8], a10[8], a11[8];
    float wx[8], wy[8];
    const float2* ob2 = off_buf + (size_t)b * HW + (size_t)ybase * W + tid;
#pragma unroll
    for (int r = 0; r < 8; ++r) {
        float2 o = ob2[r * W];
        float xf = floorf(o.x), yf = floorf(o.y);
        wx[r] = o.x - xf; wy[r] = o.y - yf;
        int x0 = (int)xf, yy0 = (int)yf;
        int x1 = min(x0 + 1, W - 1), yy1 = min(yy0 + 1, H - 1);
        int r0 = (yy0 - lo) << 8, r1 = (yy1 - lo) << 8;
        a00[r] = r0 + x0; a01[r] = r0 + x1;
        a10[r] = r1 + x0; a11[r] = r1 + x1;
    }

    const float* xb = x + ((size_t)b * C + cg * 4) * HW;
    float* outb = out + ((size_t)b * C + cg * 4) * HW + (size_t)ybase * W + tid;

#pragma unroll 1
    for (int c = 0; c < 4; ++c) {
        __syncthreads();
        const float* src = xb + (size_t)c * HW;
        for (int j = tid; j < SROWS * 64; j += 256) {
            int row = j >> 6, x4 = (j & 63) << 2;
            int grw = min(max(lo + row, 0), H - 1);
            *(float4*)&xs[(row << 8) + x4] = *(const float4*)(src + (size_t)grw * W + x4);
        }
        __syncthreads();
        float* oc = outb + (size_t)c * HW;
#pragma unroll
        for (int r = 0; r < 8; ++r) {
            float v00 = xs[a00[r]], v01 = xs[a01[r]];
            float v10 = xs[a10[r]], v11 = xs[a11[r]];
            float top = fmaf(wx[r], v01 - v00, v00);
            float bot = fmaf(wx[r], v11 - v10, v10);
            oc[r * W] = fmaf(wy[r], bot - top, top);
        }
    }
}

// ---------------------------------------------------------------------------
extern "C" void kernel_launch(void* const* d_in, const int* in_sizes, int n_in,
                              void* d_out, int out_size, void* d_ws, size_t ws_size,
                              hipStream_t stream) {
    const float* x  = (const float*)d_in[0];
    const float* w1 = (const float*)d_in[1];
    const float* b1 = (const float*)d_in[2];
    const float* w2 = (const float*)d_in[3];
    const float* b2 = (const float*)d_in[4];
    float* out = (float*)d_out;

    float* ws  = (float*)d_ws;
    float* wt  = ws;                                         // 16384 floats
    float* sim = ws + 16384;                                 // B*9*HW
    float* h   = sim + (size_t)B * 9 * HW;                   // B*16*HW
    float2* off_buf = (float2*)(h + (size_t)B * CMID * HW);  // B*HW float2

    transpose_w1_kernel<<<(NW + 255) / 256, 256, 0, stream>>>(w1, wt);

    sim_kernel<<<512, 256, 0, stream>>>(x, sim);
    conv1_kernel<<<512, 256, 0, stream>>>(x, sim, wt, b1, h);
    offset_kernel<<<512, 256, 0, stream>>>(h, w2, b2, off_buf);
    sample_kernel<<<dim3(128, 16), 256, 0, stream>>>(x, off_buf, out);
}